// Round 6
// baseline (802.674 us; speedup 1.0000x reference)
//
#include <hip/hip_runtime.h>

#define NB 8
#define NS 1024
#define NH 32
#define NKV 8
#define ND 128
#define QT 256     // per block: 8 waves x 32 q-rows
#define KT 64

typedef _Float16 f16x8 __attribute__((ext_vector_type(8)));
typedef _Float16 f16x4 __attribute__((ext_vector_type(4)));
typedef _Float16 f16x2 __attribute__((ext_vector_type(2)));
typedef __fp16 fp16x2 __attribute__((ext_vector_type(2)));
typedef float f32x16 __attribute__((ext_vector_type(16)));
typedef unsigned int u32x2 __attribute__((ext_vector_type(2)));

__device__ __forceinline__ float exp2fast(float x) { return __builtin_amdgcn_exp2f(x); }

__device__ __forceinline__ unsigned pkrtz_u(float a, float b) {
  union { fp16x2 h; unsigned u; } c;
  c.h = __builtin_amdgcn_cvt_pkrtz(a, b);
  return c.u;
}
__device__ __forceinline__ u32x2 swap32(float x) {
  union { float f; unsigned u; } c; c.f = x;
  return __builtin_amdgcn_permlane32_swap(c.u, c.u, false, false);
}
__device__ __forceinline__ float asf(unsigned u) { union { unsigned u; float f; } c; c.u = u; return c.f; }
// 3-bit chunk swizzle for 128B V^T rows
__device__ __forceinline__ int gsw3(int d) { return ((d ^ (d >> 3)) & 7) << 4; }

__global__ __launch_bounds__(512, 4)
void attn_fwd(const float* __restrict__ qg, const float* __restrict__ kg,
              const float* __restrict__ vg, float* __restrict__ og)
{
  // double-buffered: K 2x16KB (64 rows x 256B, byte ^= (kv&15)<<4),
  //                  V^T 2x16KB (128 d-rows x 128B, chunk ^= gsw3(d))  -> 64KB total, 2 blocks/CU
  __shared__ __align__(16) _Float16 Klds[2][KT * 128];
  __shared__ __align__(16) _Float16 VTlds[2][128 * 64];

  const int tid  = threadIdx.x;
  const int lane = tid & 63;
  const int w    = tid >> 6;
  const int lq   = lane & 31;
  const int hi   = lane >> 5;

  const int qtile = blockIdx.x;   // 0..3
  const int b     = blockIdx.y;
  const int h     = blockIdx.z;
  const int hkv   = h >> 2;

  const int qr0w = qtile * QT + w * 32;
  const int qrow = qr0w + lq;

  const float QS = 0.08838834764831845f * 1.4426950408889634f;  // scale * log2(e)

  // ---- Q fragments (B-frag: col=q=lane&31, k = 8*hi + i per 16-d block) ----
  f16x8 qf[8];
  {
    const float* qp = qg + (size_t)(b * NS + qrow) * (NH * ND) + h * ND + hi * 8;
#pragma unroll
    for (int dblk = 0; dblk < 8; ++dblk) {
      float4 f0 = *(const float4*)(qp + dblk * 16);
      float4 f1 = *(const float4*)(qp + dblk * 16 + 4);
      f16x8 a;
      a[0] = (_Float16)(f0.x * QS); a[1] = (_Float16)(f0.y * QS);
      a[2] = (_Float16)(f0.z * QS); a[3] = (_Float16)(f0.w * QS);
      a[4] = (_Float16)(f1.x * QS); a[5] = (_Float16)(f1.y * QS);
      a[6] = (_Float16)(f1.z * QS); a[7] = (_Float16)(f1.w * QS);
      qf[dblk] = a;
    }
  }

  f32x16 acc[4];
#pragma unroll
  for (int nb = 0; nb < 4; ++nb)
#pragma unroll
    for (int r = 0; r < 16; ++r) acc[nb][r] = 0.f;
  float m_run = -1e30f, l_run = 0.f;

  const float* kbase0 = kg + (size_t)(b * NS) * (NKV * ND) + hkv * ND;
  const float* vbase0 = vg + (size_t)(b * NS) * (NKV * ND) + hkv * ND;

  const int kvq_s = tid >> 5;          // staging decomposition for V (quad of kv rows)
  const int d4_s  = (tid & 31) * 4;

  float kpre[4][4], vpre[4][4];        // in-flight prefetch registers

#define ISSUE_TILE(KV0)                                                              \
  {                                                                                  \
    const float* kb_ = kbase0 + (size_t)(KV0) * (NKV * ND);                          \
    _Pragma("unroll")                                                                \
    for (int it = 0; it < 4; ++it) {                                                 \
      int f = tid + it * 512;                                                        \
      float4 t = *(const float4*)(kb_ + (size_t)(f >> 5) * (NKV * ND) + (f & 31) * 4); \
      kpre[it][0] = t.x; kpre[it][1] = t.y; kpre[it][2] = t.z; kpre[it][3] = t.w;    \
    }                                                                                \
    const float* vb_ = vbase0 + (size_t)(KV0) * (NKV * ND);                          \
    _Pragma("unroll")                                                                \
    for (int r = 0; r < 4; ++r) {                                                    \
      float4 t = *(const float4*)(vb_ + (size_t)(4 * kvq_s + r) * (NKV * ND) + d4_s); \
      vpre[r][0] = t.x; vpre[r][1] = t.y; vpre[r][2] = t.z; vpre[r][3] = t.w;        \
    }                                                                                \
  }

#define WRITE_TILE(BUF)                                                              \
  {                                                                                  \
    char* Kb = (char*)&Klds[BUF][0];                                                 \
    _Pragma("unroll")                                                                \
    for (int it = 0; it < 4; ++it) {                                                 \
      int f = tid + it * 512; int kvr = f >> 5; int d4 = (f & 31) * 4;               \
      union { f16x4 h; unsigned long long u; } pk;                                   \
      pk.h[0] = (_Float16)kpre[it][0]; pk.h[1] = (_Float16)kpre[it][1];              \
      pk.h[2] = (_Float16)kpre[it][2]; pk.h[3] = (_Float16)kpre[it][3];              \
      *(unsigned long long*)(Kb + kvr * 256 + ((d4 * 2) ^ ((kvr & 15) << 4))) = pk.u; \
    }                                                                                \
    char* Vb = (char*)&VTlds[BUF][0];                                                \
    _Pragma("unroll")                                                                \
    for (int i = 0; i < 4; ++i) {                                                    \
      int d = d4_s + i;                                                              \
      union { f16x4 h; unsigned long long u; } pv;                                   \
      pv.h[0] = (_Float16)vpre[0][i]; pv.h[1] = (_Float16)vpre[1][i];                \
      pv.h[2] = (_Float16)vpre[2][i]; pv.h[3] = (_Float16)vpre[3][i];                \
      *(unsigned long long*)(Vb + d * 128 + ((kvq_s * 8) ^ gsw3(d))) = pv.u;         \
    }                                                                                \
  }

  const int nt = (qtile + 1) * (QT / KT);

  // ---- prologue: stage tile 0 into buffer 0 ----
  ISSUE_TILE(0);
  WRITE_TILE(0);
  __syncthreads();

  for (int ti = 0; ti < nt; ++ti) {
    const int kv0 = ti * KT;
    const int cur = ti & 1;
    const bool hn = (ti + 1 < nt);

    if (hn) ISSUE_TILE(kv0 + KT);     // T14: loads in flight under compute

    if (kv0 <= qr0w + 31) {           // wave-uniform causal tile skip
      const char* Kb = (const char*)&Klds[cur][0];
      const char* Vb = (const char*)&VTlds[cur][0];

      // ---- swapped QK^T: P^T[kv][q] ----
      f32x16 s[2];
#pragma unroll
      for (int r = 0; r < 16; ++r) { s[0][r] = 0.f; s[1][r] = 0.f; }
      __builtin_amdgcn_s_setprio(1);
#pragma unroll
      for (int dblk = 0; dblk < 8; ++dblk) {
        int soff = (dblk * 32 + 16 * hi) ^ ((lq & 15) << 4);
        f16x8 k0 = *(const f16x8*)(Kb + lq * 256 + soff);
        f16x8 k1 = *(const f16x8*)(Kb + (lq + 32) * 256 + soff);
        s[0] = __builtin_amdgcn_mfma_f32_32x32x16_f16(k0, qf[dblk], s[0], 0, 0, 0);
        s[1] = __builtin_amdgcn_mfma_f32_32x32x16_f16(k1, qf[dblk], s[1], 0, 0, 0);
      }
      __builtin_amdgcn_s_setprio(0);

      // ---- causal mask (diagonal tiles only) ----
      if (kv0 + KT - 1 > qr0w) {
        const int thr = qrow - kv0;
#pragma unroll
        for (int kb = 0; kb < 2; ++kb)
#pragma unroll
          for (int r = 0; r < 16; ++r) {
            int kvl = kb * 32 + (r & 3) + 8 * (r >> 2) + 4 * hi;
            if (kvl > thr) s[kb][r] = -1e30f;
          }
      }

      // ---- online softmax with defer-max (T13, THR=8 in log2 units) ----
      float pmax = s[0][0];
#pragma unroll
      for (int r = 1; r < 16; ++r) pmax = fmaxf(pmax, s[0][r]);
#pragma unroll
      for (int r = 0; r < 16; ++r) pmax = fmaxf(pmax, s[1][r]);
      {
        u32x2 pr = swap32(pmax);
        pmax = fmaxf(asf(pr[0]), asf(pr[1]));
      }
      const int need = !__all(pmax <= m_run + 8.0f);
      float al = 1.0f;
      if (need) {
        const float mn = fmaxf(m_run, pmax);
        al = exp2fast(m_run - mn);
        m_run = mn;
      }
      float rs = 0.f;
#pragma unroll
      for (int kb = 0; kb < 2; ++kb)
#pragma unroll
        for (int r = 0; r < 16; ++r) {
          float p = exp2fast(s[kb][r] - m_run);
          s[kb][r] = p;
          rs += p;
        }
      {
        u32x2 sr = swap32(rs);
        rs = asf(sr[0]) + asf(sr[1]);
      }
      if (need) {
        float albc[16];
#pragma unroll
        for (int r = 0; r < 16; ++r) {
          int row = (r & 3) + 8 * (r >> 2) + 4 * hi;
          albc[r] = __shfl(al, row, 64);
        }
#pragma unroll
        for (int nb = 0; nb < 4; ++nb)
#pragma unroll
          for (int r = 0; r < 16; ++r) acc[nb][r] *= albc[r];
        l_run = l_run * al + rs;
      } else {
        l_run += rs;
      }

      // ---- P -> A-fragments in-register (cvt_pk + permlane32_swap) ----
      f16x8 pa[4];
#pragma unroll
      for (int t = 0; t < 4; ++t) {
        const int kb = t >> 1, rb = (t & 1) * 8;
        unsigned w0 = pkrtz_u(s[kb][rb + 0], s[kb][rb + 1]);
        unsigned w1 = pkrtz_u(s[kb][rb + 2], s[kb][rb + 3]);
        unsigned w2 = pkrtz_u(s[kb][rb + 4], s[kb][rb + 5]);
        unsigned w3 = pkrtz_u(s[kb][rb + 6], s[kb][rb + 7]);
        u32x2 p02 = __builtin_amdgcn_permlane32_swap(w0, w2, false, false);
        u32x2 p13 = __builtin_amdgcn_permlane32_swap(w1, w3, false, false);
        union { unsigned u[4]; f16x8 v; } pw;
        pw.u[0] = p02[0]; pw.u[1] = p13[0]; pw.u[2] = p02[1]; pw.u[3] = p13[1];
        pa[t] = pw.v;
      }

      // ---- O += P V ----
      __builtin_amdgcn_s_setprio(1);
#pragma unroll
      for (int t = 0; t < 4; ++t) {
        int koff = t * 32 + 16 * hi;
#pragma unroll
        for (int nb = 0; nb < 4; ++nb) {
          int d = nb * 32 + lq;
          f16x8 vb = *(const f16x8*)(Vb + d * 128 + (koff ^ gsw3(d)));
          acc[nb] = __builtin_amdgcn_mfma_f32_32x32x16_f16(pa[t], vb, acc[nb], 0, 0, 0);
        }
      }
      __builtin_amdgcn_s_setprio(0);
    }

    if (hn) WRITE_TILE(cur ^ 1);      // into the other buffer; no WAR with compute(cur)
    __syncthreads();                  // one barrier per tile
  }

  // ---- epilogue: divide by l, coalesced f32 stores ----
  const float linv = 1.0f / l_run;
  float lbc[16];
#pragma unroll
  for (int r = 0; r < 16; ++r) {
    int row = (r & 3) + 8 * (r >> 2) + 4 * hi;
    lbc[r] = __shfl(linv, row, 64);
  }
#pragma unroll
  for (int r = 0; r < 16; ++r) {
    int row = qr0w + (r & 3) + 8 * (r >> 2) + 4 * hi;
    float* op = og + (size_t)(b * NS + row) * (NH * ND) + h * ND + lq;
#pragma unroll
    for (int nb = 0; nb < 4; ++nb)
      op[nb * 32] = acc[nb][r] * lbc[r];
  }
}

extern "C" void kernel_launch(void* const* d_in, const int* in_sizes, int n_in,
                              void* d_out, int out_size, void* d_ws, size_t ws_size,
                              hipStream_t stream) {
  const float* q = (const float*)d_in[0];
  const float* k = (const float*)d_in[1];
  const float* v = (const float*)d_in[2];
  float* o = (float*)d_out;
  dim3 grid(NS / QT, NB, NH);
  attn_fwd<<<grid, 512, 0, stream>>>(q, k, v, o);
}

// Round 7
// 189.683 us; speedup vs baseline: 4.2317x; 4.2317x over previous
//
#include <hip/hip_runtime.h>

#define NB 8
#define NS 1024
#define NH 32
#define NKV 8
#define ND 128
#define QT 256     // per block: 8 waves x 32 q-rows
#define KT 64

typedef _Float16 f16x8 __attribute__((ext_vector_type(8)));
typedef _Float16 f16x4 __attribute__((ext_vector_type(4)));
typedef _Float16 f16x2 __attribute__((ext_vector_type(2)));
typedef __fp16 fp16x2 __attribute__((ext_vector_type(2)));
typedef float f32x16 __attribute__((ext_vector_type(16)));
typedef unsigned int u32x2 __attribute__((ext_vector_type(2)));

__device__ __forceinline__ float exp2fast(float x) { return __builtin_amdgcn_exp2f(x); }

__device__ __forceinline__ unsigned pkrtz_u(float a, float b) {
  union { fp16x2 h; unsigned u; } c;
  c.h = __builtin_amdgcn_cvt_pkrtz(a, b);
  return c.u;
}
__device__ __forceinline__ u32x2 swap32(float x) {
  union { float f; unsigned u; } c; c.f = x;
  return __builtin_amdgcn_permlane32_swap(c.u, c.u, false, false);
}
__device__ __forceinline__ float asf(unsigned u) { union { unsigned u; float f; } c; c.u = u; return c.f; }
// 3-bit chunk swizzle for 128B V^T rows
__device__ __forceinline__ int gsw3(int d) { return ((d ^ (d >> 3)) & 7) << 4; }

__global__ __launch_bounds__(512, 1)   // (512,4) forced VGPR=64 -> massive spills (R6); natural alloc is ~128
void attn_fwd(const float* __restrict__ qg, const float* __restrict__ kg,
              const float* __restrict__ vg, float* __restrict__ og)
{
  // double-buffered: K 2x16KB (64 rows x 256B, byte ^= (kv&15)<<4),
  //                  V^T 2x16KB (128 d-rows x 128B, chunk ^= gsw3(d))  -> 64KB total, 2 blocks/CU
  __shared__ __align__(16) _Float16 Klds[2][KT * 128];
  __shared__ __align__(16) _Float16 VTlds[2][128 * 64];

  const int tid  = threadIdx.x;
  const int lane = tid & 63;
  const int w    = tid >> 6;
  const int lq   = lane & 31;
  const int hi   = lane >> 5;

  const int qtile = blockIdx.x;   // 0..3
  const int b     = blockIdx.y;
  const int h     = blockIdx.z;
  const int hkv   = h >> 2;

  const int qr0w = qtile * QT + w * 32;
  const int qrow = qr0w + lq;

  const float QS = 0.08838834764831845f * 1.4426950408889634f;  // scale * log2(e)

  // ---- Q fragments (B-frag: col=q=lane&31, k = 8*hi + i per 16-d block) ----
  f16x8 qf[8];
  {
    const float* qp = qg + (size_t)(b * NS + qrow) * (NH * ND) + h * ND + hi * 8;
#pragma unroll
    for (int dblk = 0; dblk < 8; ++dblk) {
      float4 f0 = *(const float4*)(qp + dblk * 16);
      float4 f1 = *(const float4*)(qp + dblk * 16 + 4);
      f16x8 a;
      a[0] = (_Float16)(f0.x * QS); a[1] = (_Float16)(f0.y * QS);
      a[2] = (_Float16)(f0.z * QS); a[3] = (_Float16)(f0.w * QS);
      a[4] = (_Float16)(f1.x * QS); a[5] = (_Float16)(f1.y * QS);
      a[6] = (_Float16)(f1.z * QS); a[7] = (_Float16)(f1.w * QS);
      qf[dblk] = a;
    }
  }

  f32x16 acc[4];
#pragma unroll
  for (int nb = 0; nb < 4; ++nb)
#pragma unroll
    for (int r = 0; r < 16; ++r) acc[nb][r] = 0.f;
  float m_run = -1e30f, l_run = 0.f;

  const float* kbase0 = kg + (size_t)(b * NS) * (NKV * ND) + hkv * ND;
  const float* vbase0 = vg + (size_t)(b * NS) * (NKV * ND) + hkv * ND;

  const int kvq_s = tid >> 5;          // staging decomposition for V (quad of kv rows)
  const int d4_s  = (tid & 31) * 4;

  float kpre[4][4], vpre[4][4];        // in-flight prefetch registers

#define ISSUE_TILE(KV0)                                                              \
  {                                                                                  \
    const float* kb_ = kbase0 + (size_t)(KV0) * (NKV * ND);                          \
    _Pragma("unroll")                                                                \
    for (int it = 0; it < 4; ++it) {                                                 \
      int f = tid + it * 512;                                                        \
      float4 t = *(const float4*)(kb_ + (size_t)(f >> 5) * (NKV * ND) + (f & 31) * 4); \
      kpre[it][0] = t.x; kpre[it][1] = t.y; kpre[it][2] = t.z; kpre[it][3] = t.w;    \
    }                                                                                \
    const float* vb_ = vbase0 + (size_t)(KV0) * (NKV * ND);                          \
    _Pragma("unroll")                                                                \
    for (int r = 0; r < 4; ++r) {                                                    \
      float4 t = *(const float4*)(vb_ + (size_t)(4 * kvq_s + r) * (NKV * ND) + d4_s); \
      vpre[r][0] = t.x; vpre[r][1] = t.y; vpre[r][2] = t.z; vpre[r][3] = t.w;        \
    }                                                                                \
  }

#define WRITE_TILE(BUF)                                                              \
  {                                                                                  \
    char* Kb = (char*)&Klds[BUF][0];                                                 \
    _Pragma("unroll")                                                                \
    for (int it = 0; it < 4; ++it) {                                                 \
      int f = tid + it * 512; int kvr = f >> 5; int d4 = (f & 31) * 4;               \
      union { f16x4 h; unsigned long long u; } pk;                                   \
      pk.h[0] = (_Float16)kpre[it][0]; pk.h[1] = (_Float16)kpre[it][1];              \
      pk.h[2] = (_Float16)kpre[it][2]; pk.h[3] = (_Float16)kpre[it][3];              \
      *(unsigned long long*)(Kb + kvr * 256 + ((d4 * 2) ^ ((kvr & 15) << 4))) = pk.u; \
    }                                                                                \
    char* Vb = (char*)&VTlds[BUF][0];                                                \
    _Pragma("unroll")                                                                \
    for (int i = 0; i < 4; ++i) {                                                    \
      int d = d4_s + i;                                                              \
      union { f16x4 h; unsigned long long u; } pv;                                   \
      pv.h[0] = (_Float16)vpre[0][i]; pv.h[1] = (_Float16)vpre[1][i];                \
      pv.h[2] = (_Float16)vpre[2][i]; pv.h[3] = (_Float16)vpre[3][i];                \
      *(unsigned long long*)(Vb + d * 128 + ((kvq_s * 8) ^ gsw3(d))) = pv.u;         \
    }                                                                                \
  }

  const int nt = (qtile + 1) * (QT / KT);

  // ---- prologue: stage tile 0 into buffer 0 ----
  ISSUE_TILE(0);
  WRITE_TILE(0);
  __syncthreads();

  for (int ti = 0; ti < nt; ++ti) {
    const int kv0 = ti * KT;
    const int cur = ti & 1;
    const bool hn = (ti + 1 < nt);

    if (hn) ISSUE_TILE(kv0 + KT);     // T14: loads in flight under compute

    if (kv0 <= qr0w + 31) {           // wave-uniform causal tile skip
      const char* Kb = (const char*)&Klds[cur][0];
      const char* Vb = (const char*)&VTlds[cur][0];

      // ---- swapped QK^T: P^T[kv][q] ----
      f32x16 s[2];
#pragma unroll
      for (int r = 0; r < 16; ++r) { s[0][r] = 0.f; s[1][r] = 0.f; }
      __builtin_amdgcn_s_setprio(1);
#pragma unroll
      for (int dblk = 0; dblk < 8; ++dblk) {
        int soff = (dblk * 32 + 16 * hi) ^ ((lq & 15) << 4);
        f16x8 k0 = *(const f16x8*)(Kb + lq * 256 + soff);
        f16x8 k1 = *(const f16x8*)(Kb + (lq + 32) * 256 + soff);
        s[0] = __builtin_amdgcn_mfma_f32_32x32x16_f16(k0, qf[dblk], s[0], 0, 0, 0);
        s[1] = __builtin_amdgcn_mfma_f32_32x32x16_f16(k1, qf[dblk], s[1], 0, 0, 0);
      }
      __builtin_amdgcn_s_setprio(0);

      // ---- causal mask (diagonal tiles only) ----
      if (kv0 + KT - 1 > qr0w) {
        const int thr = qrow - kv0;
#pragma unroll
        for (int kb = 0; kb < 2; ++kb)
#pragma unroll
          for (int r = 0; r < 16; ++r) {
            int kvl = kb * 32 + (r & 3) + 8 * (r >> 2) + 4 * hi;
            if (kvl > thr) s[kb][r] = -1e30f;
          }
      }

      // ---- online softmax with defer-max (T13, THR=8 in log2 units) ----
      float pmax = s[0][0];
#pragma unroll
      for (int r = 1; r < 16; ++r) pmax = fmaxf(pmax, s[0][r]);
#pragma unroll
      for (int r = 0; r < 16; ++r) pmax = fmaxf(pmax, s[1][r]);
      {
        u32x2 pr = swap32(pmax);
        pmax = fmaxf(asf(pr[0]), asf(pr[1]));
      }
      const int need = !__all(pmax <= m_run + 8.0f);
      float al = 1.0f;
      if (need) {
        const float mn = fmaxf(m_run, pmax);
        al = exp2fast(m_run - mn);
        m_run = mn;
      }
      float rs = 0.f;
#pragma unroll
      for (int kb = 0; kb < 2; ++kb)
#pragma unroll
        for (int r = 0; r < 16; ++r) {
          float p = exp2fast(s[kb][r] - m_run);
          s[kb][r] = p;
          rs += p;
        }
      {
        u32x2 sr = swap32(rs);
        rs = asf(sr[0]) + asf(sr[1]);
      }
      if (need) {
        float albc[16];
#pragma unroll
        for (int r = 0; r < 16; ++r) {
          int row = (r & 3) + 8 * (r >> 2) + 4 * hi;
          albc[r] = __shfl(al, row, 64);
        }
#pragma unroll
        for (int nb = 0; nb < 4; ++nb)
#pragma unroll
          for (int r = 0; r < 16; ++r) acc[nb][r] *= albc[r];
        l_run = l_run * al + rs;
      } else {
        l_run += rs;
      }

      // ---- P -> A-fragments in-register (cvt_pk + permlane32_swap) ----
      f16x8 pa[4];
#pragma unroll
      for (int t = 0; t < 4; ++t) {
        const int kb = t >> 1, rb = (t & 1) * 8;
        unsigned w0 = pkrtz_u(s[kb][rb + 0], s[kb][rb + 1]);
        unsigned w1 = pkrtz_u(s[kb][rb + 2], s[kb][rb + 3]);
        unsigned w2 = pkrtz_u(s[kb][rb + 4], s[kb][rb + 5]);
        unsigned w3 = pkrtz_u(s[kb][rb + 6], s[kb][rb + 7]);
        u32x2 p02 = __builtin_amdgcn_permlane32_swap(w0, w2, false, false);
        u32x2 p13 = __builtin_amdgcn_permlane32_swap(w1, w3, false, false);
        union { unsigned u[4]; f16x8 v; } pw;
        pw.u[0] = p02[0]; pw.u[1] = p13[0]; pw.u[2] = p02[1]; pw.u[3] = p13[1];
        pa[t] = pw.v;
      }

      // ---- O += P V ----
      __builtin_amdgcn_s_setprio(1);
#pragma unroll
      for (int t = 0; t < 4; ++t) {
        int koff = t * 32 + 16 * hi;
#pragma unroll
        for (int nb = 0; nb < 4; ++nb) {
          int d = nb * 32 + lq;
          f16x8 vb = *(const f16x8*)(Vb + d * 128 + (koff ^ gsw3(d)));
          acc[nb] = __builtin_amdgcn_mfma_f32_32x32x16_f16(pa[t], vb, acc[nb], 0, 0, 0);
        }
      }
      __builtin_amdgcn_s_setprio(0);
    }

    if (hn) WRITE_TILE(cur ^ 1);      // into the other buffer; no WAR with compute(cur)
    __syncthreads();                  // one barrier per tile
  }

  // ---- epilogue: divide by l, coalesced f32 stores ----
  const float linv = 1.0f / l_run;
  float lbc[16];
#pragma unroll
  for (int r = 0; r < 16; ++r) {
    int row = (r & 3) + 8 * (r >> 2) + 4 * hi;
    lbc[r] = __shfl(linv, row, 64);
  }
#pragma unroll
  for (int r = 0; r < 16; ++r) {
    int row = qr0w + (r & 3) + 8 * (r >> 2) + 4 * hi;
    float* op = og + (size_t)(b * NS + row) * (NH * ND) + h * ND + lq;
#pragma unroll
    for (int nb = 0; nb < 4; ++nb)
      op[nb * 32] = acc[nb][r] * lbc[r];
  }
}

extern "C" void kernel_launch(void* const* d_in, const int* in_sizes, int n_in,
                              void* d_out, int out_size, void* d_ws, size_t ws_size,
                              hipStream_t stream) {
  const float* q = (const float*)d_in[0];
  const float* k = (const float*)d_in[1];
  const float* v = (const float*)d_in[2];
  float* o = (float*)d_out;
  dim3 grid(NS / QT, NB, NH);
  attn_fwd<<<grid, 512, 0, stream>>>(q, k, v, o);
}